// Round 19
// baseline (148.422 us; speedup 1.0000x reference)
//
#include <hip/hip_runtime.h>

typedef __attribute__((ext_vector_type(8))) short bf16x8;
typedef __attribute__((ext_vector_type(4))) float f32x4;
typedef __attribute__((ext_vector_type(4))) unsigned short us4;

#define T_SEQ 2048
#define DMODEL 2048
#define NH 16
#define NKV 4
#define HD 128
#define STRQKV 5120   /* NH*HD*2 + 2*NKV*HD : fused QKV output row stride */
#define KOFF 4096
#define VOFF 4608
#define ATT_SCALE 0.08838834764831845f
#define LOG2E 1.4426950408889634f

__device__ __forceinline__ float bf2f(unsigned short u) {
  union { unsigned int u; float f; } v; v.u = ((unsigned int)u) << 16; return v.f;
}
__device__ __forceinline__ unsigned short f2bf(float f) {
  union { float f; unsigned int u; } v; v.f = f;
  unsigned int u = v.u;
  return (unsigned short)((u + 0x7fffu + ((u >> 16) & 1u)) >> 16);
}
__device__ __forceinline__ f32x4 mfma16(bf16x8 a, bf16x8 b, f32x4 c) {
  return __builtin_amdgcn_mfma_f32_16x16x32_bf16(a, b, c, 0, 0, 0);
}
__device__ __forceinline__ void gload16(const void* g, void* l) {
  __builtin_amdgcn_global_load_lds(
      (const __attribute__((address_space(1))) unsigned int*)g,
      (__attribute__((address_space(3))) unsigned int*)l, 16, 0, 0);
}

// ---------------- fused prologue: convert hidden + transpose wq/wk/wv(/wo) ----------------
__global__ __launch_bounds__(256) void prep(
    const float* __restrict__ hidden, const float* __restrict__ wq,
    const float* __restrict__ wk, const float* __restrict__ wv,
    const float* __restrict__ wo,
    unsigned short* __restrict__ Xb, unsigned short* __restrict__ Wqkvt,
    unsigned short* __restrict__ Wot) {
  const int bid = blockIdx.x;
  const int tid = threadIdx.x;
  if (bid < 4096) {  // fp32 -> bf16 convert, float4/thread
    int i = bid * 256 + tid;
    float4 v = ((const float4*)hidden)[i];
    us4 o; o.x = f2bf(v.x); o.y = f2bf(v.y); o.z = f2bf(v.z); o.w = f2bf(v.w);
    ((us4*)Xb)[i] = o;
    return;
  }
  const float* in; unsigned short* out; int N, lb;
  if (bid < 12288)      { in = wq; out = Wqkvt;                          N = 4096; lb = bid - 4096; }
  else if (bid < 13312) { in = wk; out = Wqkvt + (size_t)KOFF * DMODEL;  N = 512;  lb = bid - 12288; }
  else if (bid < 14336) { in = wv; out = Wqkvt + (size_t)VOFF * DMODEL;  N = 512;  lb = bid - 13312; }
  else                  { in = wo; out = Wot;                            N = 2048; lb = bid - 14336; }
  const int ntb = N >> 5;
  const int nb = (lb % ntb) * 32, kb = (lb / ntb) * 32;
  __shared__ unsigned short tile[32][33];
  const int tx = tid & 31, ty = tid >> 5;
#pragma unroll
  for (int i = 0; i < 32; i += 8)
    tile[ty + i][tx] = f2bf(in[(size_t)(kb + ty + i) * N + nb + tx]);
  __syncthreads();
#pragma unroll
  for (int i = 0; i < 32; i += 8)
    out[(size_t)(nb + ty + i) * DMODEL + kb + tx] = tile[tx][ty + i];
}

// fallback wo transpose (when ws too small to host Wot separately pre-GEMM)
__global__ __launch_bounds__(256) void transpose_wo(
    const float* __restrict__ in, unsigned short* __restrict__ out) {
  __shared__ unsigned short tile[32][33];
  int nb = blockIdx.x * 32, kb = blockIdx.y * 32;
  int tx = threadIdx.x & 31, ty = threadIdx.x >> 5;
#pragma unroll
  for (int i = 0; i < 32; i += 8)
    tile[ty + i][tx] = f2bf(in[(size_t)(kb + ty + i) * DMODEL + nb + tx]);
  __syncthreads();
#pragma unroll
  for (int i = 0; i < 32; i += 8)
    out[(size_t)(nb + ty + i) * DMODEL + kb + tx] = tile[tx][ty + i];
}

// ---------------- fused K-RMSNorm+RoPE (in place) + V transpose ----------------
__global__ __launch_bounds__(256) void normtv(
    unsigned short* __restrict__ qkv, unsigned short* __restrict__ vTg,
    const float* __restrict__ cosb, const float* __restrict__ sinb,
    const float* __restrict__ knw) {
  const int bid = blockIdx.x;
  const int tid = threadIdx.x;
  if (bid < 4096) {
    const int sub = tid >> 7, d = tid & 127;
    const int j = bid * 2 + sub;            // 0..8191
    const int t = j >> 2, kh = j & 3;
    size_t addr = (size_t)t * STRQKV + KOFF + kh * HD + d;
    float x = bf2f(qkv[addr]);
    float ss = x * x;
#pragma unroll
    for (int mk = 1; mk < 64; mk <<= 1) ss += __shfl_xor(ss, mk, 64);
    __shared__ float red[4];
    __shared__ float xs[256];
    if ((tid & 63) == 0) red[tid >> 6] = ss;
    __syncthreads();
    float rstd = rsqrtf((red[sub * 2] + red[sub * 2 + 1]) * (1.0f / 128.0f) + 1e-6f);
    float xn = x * rstd * knw[d];
    xs[tid] = xn;
    __syncthreads();
    float other = (d < 64) ? -xs[sub * 128 + d + 64] : xs[sub * 128 + d - 64];
    qkv[addr] = f2bf(xn * cosb[(size_t)t * HD + d] + other * sinb[(size_t)t * HD + d]);
    return;
  }
  const int lb = bid - 4096;                 // 0..1023
  const int tb = (lb & 63) * 32, db = ((lb >> 6) & 3) * 32, kvh = lb >> 8;
  __shared__ unsigned short tile[32][33];
  const int tx = tid & 31, ty = tid >> 5;
#pragma unroll
  for (int i = 0; i < 32; i += 8)
    tile[ty + i][tx] = qkv[(size_t)(tb + ty + i) * STRQKV + VOFF + kvh * HD + db + tx];
  __syncthreads();
#pragma unroll
  for (int i = 0; i < 32; i += 8)
    vTg[((size_t)kvh * HD + db + ty + i) * T_SEQ + tb + tx] = tile[tx][ty + i];
}

// ---------------- GEMM (BK=64): 128xBN tile, 8 waves, 2-buffer staging ----------------
// Chunk-XOR involution (ch ^= row&7) on both staging source and ds_read side:
// conflict-free (measured SQ_LDS_BANK_CONFLICT = 0). Half the barriers of BK=32.
template <int BN, typename OT>
__global__ __launch_bounds__(512) void gemm_bt64(const unsigned short* __restrict__ A,
                                                 const unsigned short* __restrict__ B,
                                                 OT* __restrict__ C, int M, int N, int K) {
  constexpr int NB = BN / 32;                 // 5 for BN=160, 4 for BN=128
  constexpr int BCH = BN * 8;                 // B 16B-chunks per tile
  __shared__ unsigned short As[2][128 * 64];  // 32 KB
  __shared__ unsigned short Bs[2][BN * 64];
  const int tid = threadIdx.x;
  const int wave = tid >> 6, lane = tid & 63;
  const int wr = wave >> 1, wc = wave & 1;
  const int g = lane >> 4, lr = lane & 15;
  const int row0 = blockIdx.y * 128, col0 = blockIdx.x * BN;

  auto stage = [&](int buf, int k0) {
#pragma unroll
    for (int i = 0; i < 2; ++i) {
      int ci = i * 512 + tid;
      int row = ci >> 3, ch = (ci & 7) ^ (row & 7);
      gload16(A + (size_t)(row0 + row) * K + k0 + ch * 8, &As[buf][ci * 8]);
    }
#pragma unroll
    for (int i = 0; i < 3; ++i) {
      int ci = i * 512 + tid;
      if (ci < BCH) {
        int row = ci >> 3, ch = (ci & 7) ^ (row & 7);
        gload16(B + (size_t)(col0 + row) * K + k0 + ch * 8, &Bs[buf][ci * 8]);
      }
    }
  };

  f32x4 acc[2][NB] = {};

  stage(0, 0);
  __syncthreads();
  int cur = 0;
  for (int k0 = 0; k0 < K; k0 += 64) {
    if (k0 + 64 < K) stage(cur ^ 1, k0 + 64);

#pragma unroll
    for (int kk = 0; kk < 2; ++kk) {
      bf16x8 af[2], bfr[NB];
#pragma unroll
      for (int m = 0; m < 2; ++m) {
        int row = wr * 32 + m * 16 + lr;
        af[m] = *(const bf16x8*)(&As[cur][row * 64 + (((kk * 4 + g) ^ (row & 7)) * 8)]);
      }
#pragma unroll
      for (int n = 0; n < NB; ++n) {
        int row = wc * (BN / 2) + n * 16 + lr;
        bfr[n] = *(const bf16x8*)(&Bs[cur][row * 64 + (((kk * 4 + g) ^ (row & 7)) * 8)]);
      }
      __builtin_amdgcn_s_setprio(1);
#pragma unroll
      for (int m = 0; m < 2; ++m)
#pragma unroll
        for (int n = 0; n < NB; ++n)
          acc[m][n] = mfma16(af[m], bfr[n], acc[m][n]);
      __builtin_amdgcn_s_setprio(0);
    }

    __syncthreads();
    cur ^= 1;
  }

#pragma unroll
  for (int m = 0; m < 2; ++m)
#pragma unroll
    for (int n = 0; n < NB; ++n)
#pragma unroll
      for (int r = 0; r < 4; ++r) {
        int row = row0 + wr * 32 + m * 16 + g * 4 + r;
        int col = col0 + wc * (BN / 2) + n * 16 + lr;
        float v = acc[m][n][r];
        if constexpr (sizeof(OT) == 2) C[(size_t)row * N + col] = f2bf(v);
        else                            C[(size_t)row * N + col] = v;
      }
}

// ---------------- Flash attention + gate (Q norm/rope fused) ----------------
// 256 blocks x 8 waves; block = (head h, pair p): waves 0-3 own q-chunk qb=p,
// waves 4-7 own q-chunk qb=31-p -> every block computes exactly 33
// wave-tile-groups (perfect load balance at 1 block/CU). KVBLK=64, 2 buffers,
// stage(next)-before-compute(cur), ONE __syncthreads/tile, no-max exp2 softmax.
__global__ __launch_bounds__(512) void attn_kernel(
    const unsigned short* __restrict__ qkv, const unsigned short* __restrict__ vTg,
    const int* __restrict__ seg,
    const float* __restrict__ cosb, const float* __restrict__ sinb,
    const float* __restrict__ qnw,
    unsigned short* __restrict__ attnb) {
  const int bid = blockIdx.x;
  const int h = bid & 15;
  const int p = bid >> 4;                 // 0..15
  const int kvh = h >> 2;
  const int tid = threadIdx.x;
  const int wave = tid >> 6, lane = tid & 63;
  const int g = lane >> 4, lr = lane & 15;
  const int qb = (wave < 4) ? p : (31 - p);           // this wave's q-chunk
  const int qrow0 = qb * 64 + (wave & 3) * 16;

  __shared__ unsigned short Ks[2][64 * 128];   // 32 KB
  __shared__ unsigned short Vt[2][128 * 64];   // 32 KB
  __shared__ unsigned short Plds[8][16][64];   // 16 KB (XOR col swizzle, no pad)

  const unsigned short* Kbase = qkv + KOFF + kvh * HD;         // row stride STRQKV
  const unsigned short* Vbase = vTg + (size_t)kvh * HD * T_SEQ;

  auto stage = [&](int buf, int kv0) {
#pragma unroll
    for (int i = 0; i < 2; ++i) {
      int row = i * 32 + (tid >> 4);            // K rows 0..63
      int c16 = (tid & 15) ^ (row & 7);
      gload16(Kbase + (size_t)(kv0 + row) * STRQKV + c16 * 8, &Ks[buf][i * 4096 + tid * 8]);
    }
#pragma unroll
    for (int i = 0; i < 2; ++i) {
      int row = i * 64 + (tid >> 3);            // V rows (d) 0..127
      int c16 = (tid & 7) ^ (row & 7);
      gload16(Vbase + (size_t)row * T_SEQ + kv0 + c16 * 8, &Vt[buf][i * 4096 + tid * 8]);
    }
  };

  const int ntiles = 32 - p;                   // (31-p)+1 : larger chunk's bound
  const int segB = seg[p * 64];                // earliest rows -> conservative
  int t_begin = 0;
  while (t_begin < ntiles - 1 && seg[t_begin * 64 + 63] < segB) ++t_begin;

  stage(0, t_begin * 64);

  // ---- fused Q RMSNorm + RoPE + scale (overlaps staging latency) ----
  const int t0 = qrow0 + lr;
  float xn[4][8];
  {
    float ssl = 0.f;
#pragma unroll
    for (int c = 0; c < 4; ++c) {
      bf16x8 tq = *(const bf16x8*)(qkv + (size_t)t0 * STRQKV + h * 256 + c * 32 + g * 8);
#pragma unroll
      for (int i = 0; i < 8; ++i) {
        float x = bf2f((unsigned short)tq[i]);
        xn[c][i] = x;
        ssl += x * x;
      }
    }
    ssl += __shfl_xor(ssl, 16, 64);
    ssl += __shfl_xor(ssl, 32, 64);
    float rstd = rsqrtf(ssl * (1.0f / 128.0f) + 1e-6f);
#pragma unroll
    for (int c = 0; c < 4; ++c)
#pragma unroll
      for (int i = 0; i < 8; ++i)
        xn[c][i] *= rstd * qnw[c * 32 + g * 8 + i];
  }
  bf16x8 qf[4];
#pragma unroll
  for (int c = 0; c < 4; ++c)
#pragma unroll
    for (int i = 0; i < 8; ++i) {
      int d = c * 32 + g * 8 + i;
      float rot = (c < 2) ? -xn[c + 2][i] : xn[c - 2][i];
      float ov = xn[c][i] * cosb[(size_t)t0 * HD + d] + rot * sinb[(size_t)t0 * HD + d];
      qf[c][i] = (short)f2bf(ov * (ATT_SCALE * LOG2E));   // log2-domain logits
    }

  bf16x8 vones;
#pragma unroll
  for (int i = 0; i < 8; ++i) vones[i] = (short)0x3F80;  // bf16 1.0

  int myrow[4], myseg[4];
#pragma unroll
  for (int r = 0; r < 4; ++r) {
    myrow[r] = qrow0 + g * 4 + r;
    myseg[r] = seg[myrow[r]];
  }
  const int seg_lo = seg[qrow0];
  const int seg_hi = seg[qrow0 + 15];

  f32x4 lacc = {};
  f32x4 oacc[8] = {};

  __syncthreads();  // first tile staged (drain)
  int cur = 0;
  for (int t = t_begin; t < ntiles; ++t) {
    const int kv0 = t * 64;
    if (t + 1 < ntiles) stage(cur ^ 1, kv0 + 64);  // overlaps compute below

    if (kv0 < qrow0 + 16 && seg[kv0 + 63] >= seg_lo) {  // wave-level causal/seg skip
      const unsigned short* ks = Ks[cur];
      const unsigned short* vt = Vt[cur];

      // ---- S = Q K^T : 16 x 64 (log2-domain) ----
      f32x4 sacc[4] = {};
      __builtin_amdgcn_s_setprio(1);
#pragma unroll
      for (int cc = 0; cc < 4; ++cc)
#pragma unroll
        for (int c = 0; c < 4; ++c) {
          int row = cc * 16 + lr;
          bf16x8 kf = *(const bf16x8*)(&ks[row * 128 + (((c * 4 + g) ^ (row & 7)) * 8)]);
          sacc[cc] = mfma16(qf[c], kf, sacc[cc]);
        }
      __builtin_amdgcn_s_setprio(0);

      // ---- P = exp2(S); Plds col' = col ^ ((row&3)<<4) ----
      const bool full = (kv0 + 64 <= qrow0) && (seg[kv0] == seg_hi);
      if (full) {
#pragma unroll
        for (int cc = 0; cc < 4; ++cc)
#pragma unroll
          for (int r = 0; r < 4; ++r)
            Plds[wave][g * 4 + r][((cc ^ r) * 16) + lr] = f2bf(exp2f(sacc[cc][r]));
      } else {
#pragma unroll
        for (int cc = 0; cc < 4; ++cc) {
          int kvi = kv0 + cc * 16 + lr;
          int ksg = seg[kvi];
#pragma unroll
          for (int r = 0; r < 4; ++r) {
            bool ok = (kvi <= myrow[r]) && (ksg == myseg[r]);
            float p2 = exp2f(sacc[cc][r]);
            Plds[wave][g * 4 + r][((cc ^ r) * 16) + lr] = f2bf(ok ? p2 : 0.0f);
          }
        }
      }

      // ---- PV: O += P[16x64] * V^T ; row-sum via ones-vector MFMA ----
      bf16x8 pf0 = *(const bf16x8*)(&Plds[wave][lr][(g * 8) ^ ((lr & 3) << 4)]);
      bf16x8 pf1 = *(const bf16x8*)(&Plds[wave][lr][(32 + g * 8) ^ ((lr & 3) << 4)]);
      __builtin_amdgcn_s_setprio(1);
#pragma unroll
      for (int n = 0; n < 8; ++n) {
        int row = n * 16 + lr;
        bf16x8 vf0 = *(const bf16x8*)(&vt[row * 64 + ((g ^ (row & 7)) * 8)]);
        oacc[n] = mfma16(pf0, vf0, oacc[n]);
        bf16x8 vf1 = *(const bf16x8*)(&vt[row * 64 + (((4 + g) ^ (row & 7)) * 8)]);
        oacc[n] = mfma16(pf1, vf1, oacc[n]);
      }
      lacc = mfma16(pf0, vones, lacc);
      lacc = mfma16(pf1, vones, lacc);
      __builtin_amdgcn_s_setprio(0);
    }

    __syncthreads();  // prefetch drained + all waves done with buf cur
    cur ^= 1;
  }

  // epilogue: normalize, sigmoid-gate, store bf16
#pragma unroll
  for (int n = 0; n < 8; ++n)
#pragma unroll
    for (int r = 0; r < 4; ++r) {
      int row = myrow[r];
      int d = n * 16 + lr;
      float o = oacc[n][r] / lacc[r];
      float gv = bf2f(qkv[(size_t)row * STRQKV + h * 256 + 128 + d]);
      float gate = 1.0f / (1.0f + __expf(-gv));
      attnb[(size_t)row * (NH * HD) + h * HD + d] = f2bf(o * gate);
    }
}

extern "C" void kernel_launch(void* const* d_in, const int* in_sizes, int n_in,
                              void* d_out, int out_size, void* d_ws, size_t ws_size,
                              hipStream_t stream) {
  const float* hidden = (const float*)d_in[0];
  const float* cosb   = (const float*)d_in[1];
  const float* sinb   = (const float*)d_in[2];
  const int*   seg    = (const int*)d_in[3];
  // d_in[4] = position_ids (arange; causal handled by index arithmetic)
  const float* wq     = (const float*)d_in[5];
  const float* wk     = (const float*)d_in[6];
  const float* wv     = (const float*)d_in[7];
  const float* wo     = (const float*)d_in[8];
  const float* qnw    = (const float*)d_in[9];
  const float* knw    = (const float*)d_in[10];
  float* out = (float*)d_out;

  // Workspace layout (liveness-aliased):
  //   [0,8)    Xb (hidden bf16)   -> dead after QKV GEMM -> Attnb
  //   [8,28)   Wqkvt [5120][2048] -> dead after QKV GEMM -> VT [16,18)
  //   [28,48)  Cqkv [2048][5120]  (q|gate|k|v; k normed/roped in place)
  //   [48,56)  Wot (only if ws_size >= 56MB; else Wot aliases [8,16) post-GEMM)
  char* ws = (char*)d_ws;
  const size_t MB = (size_t)1 << 20;
  const bool big = ws_size >= 56 * MB;
  unsigned short* Xb    = (unsigned short*)(ws + 0 * MB);
  unsigned short* Attnb = (unsigned short*)(ws + 0 * MB);
  unsigned short* Wqkvt = (unsigned short*)(ws + 8 * MB);
  unsigned short* VT    = (unsigned short*)(ws + 16 * MB);
  unsigned short* Cqkv  = (unsigned short*)(ws + 28 * MB);
  unsigned short* Wot   = (unsigned short*)(big ? (ws + 48 * MB) : (ws + 8 * MB));

  prep<<<big ? 18432 : 14336, 256, 0, stream>>>(hidden, wq, wk, wv, wo, Xb, Wqkvt, Wot);

  gemm_bt64<160, unsigned short><<<dim3(STRQKV / 160, T_SEQ / 128), 512, 0, stream>>>(Xb, Wqkvt, Cqkv, T_SEQ, STRQKV, DMODEL);

  if (!big)
    transpose_wo<<<dim3(DMODEL / 32, DMODEL / 32), 256, 0, stream>>>(wo, Wot);

  normtv<<<5120, 256, 0, stream>>>(Cqkv, VT, cosb, sinb, knw);

  attn_kernel<<<256, 512, 0, stream>>>(Cqkv, VT, seg, cosb, sinb, qnw, Attnb);

  gemm_bt64<128, float><<<dim3(DMODEL / 128, T_SEQ / 128), 512, 0, stream>>>(Attnb, Wot, out, T_SEQ, DMODEL, DMODEL);
}

// Round 20
// 136.364 us; speedup vs baseline: 1.0884x; 1.0884x over previous
//
#include <hip/hip_runtime.h>

typedef __attribute__((ext_vector_type(8))) short bf16x8;
typedef __attribute__((ext_vector_type(4))) float f32x4;
typedef __attribute__((ext_vector_type(4))) unsigned short us4;

#define T_SEQ 2048
#define DMODEL 2048
#define NH 16
#define NKV 4
#define HD 128
#define STRQKV 5120   /* NH*HD*2 + 2*NKV*HD : fused QKV output row stride */
#define KOFF 4096
#define VOFF 4608
#define ATT_SCALE 0.08838834764831845f
#define LOG2E 1.4426950408889634f

__device__ __forceinline__ float bf2f(unsigned short u) {
  union { unsigned int u; float f; } v; v.u = ((unsigned int)u) << 16; return v.f;
}
__device__ __forceinline__ unsigned short f2bf(float f) {
  union { float f; unsigned int u; } v; v.f = f;
  unsigned int u = v.u;
  return (unsigned short)((u + 0x7fffu + ((u >> 16) & 1u)) >> 16);
}
__device__ __forceinline__ f32x4 mfma16(bf16x8 a, bf16x8 b, f32x4 c) {
  return __builtin_amdgcn_mfma_f32_16x16x32_bf16(a, b, c, 0, 0, 0);
}
__device__ __forceinline__ void gload16(const void* g, void* l) {
  __builtin_amdgcn_global_load_lds(
      (const __attribute__((address_space(1))) unsigned int*)g,
      (__attribute__((address_space(3))) unsigned int*)l, 16, 0, 0);
}

// ---------------- fused prologue: convert hidden + transpose wq/wk/wv(/wo) ----------------
__global__ __launch_bounds__(256) void prep(
    const float* __restrict__ hidden, const float* __restrict__ wq,
    const float* __restrict__ wk, const float* __restrict__ wv,
    const float* __restrict__ wo,
    unsigned short* __restrict__ Xb, unsigned short* __restrict__ Wqkvt,
    unsigned short* __restrict__ Wot) {
  const int bid = blockIdx.x;
  const int tid = threadIdx.x;
  if (bid < 4096) {  // fp32 -> bf16 convert, float4/thread
    int i = bid * 256 + tid;
    float4 v = ((const float4*)hidden)[i];
    us4 o; o.x = f2bf(v.x); o.y = f2bf(v.y); o.z = f2bf(v.z); o.w = f2bf(v.w);
    ((us4*)Xb)[i] = o;
    return;
  }
  const float* in; unsigned short* out; int N, lb;
  if (bid < 12288)      { in = wq; out = Wqkvt;                          N = 4096; lb = bid - 4096; }
  else if (bid < 13312) { in = wk; out = Wqkvt + (size_t)KOFF * DMODEL;  N = 512;  lb = bid - 12288; }
  else if (bid < 14336) { in = wv; out = Wqkvt + (size_t)VOFF * DMODEL;  N = 512;  lb = bid - 13312; }
  else                  { in = wo; out = Wot;                            N = 2048; lb = bid - 14336; }
  const int ntb = N >> 5;
  const int nb = (lb % ntb) * 32, kb = (lb / ntb) * 32;
  __shared__ unsigned short tile[32][33];
  const int tx = tid & 31, ty = tid >> 5;
#pragma unroll
  for (int i = 0; i < 32; i += 8)
    tile[ty + i][tx] = f2bf(in[(size_t)(kb + ty + i) * N + nb + tx]);
  __syncthreads();
#pragma unroll
  for (int i = 0; i < 32; i += 8)
    out[(size_t)(nb + ty + i) * DMODEL + kb + tx] = tile[tx][ty + i];
}

// fallback wo transpose (when ws too small to host Wot separately pre-GEMM)
__global__ __launch_bounds__(256) void transpose_wo(
    const float* __restrict__ in, unsigned short* __restrict__ out) {
  __shared__ unsigned short tile[32][33];
  int nb = blockIdx.x * 32, kb = blockIdx.y * 32;
  int tx = threadIdx.x & 31, ty = threadIdx.x >> 5;
#pragma unroll
  for (int i = 0; i < 32; i += 8)
    tile[ty + i][tx] = f2bf(in[(size_t)(kb + ty + i) * DMODEL + nb + tx]);
  __syncthreads();
#pragma unroll
  for (int i = 0; i < 32; i += 8)
    out[(size_t)(nb + ty + i) * DMODEL + kb + tx] = tile[tx][ty + i];
}

// ---------------- fused K-RMSNorm+RoPE (in place) + V transpose ----------------
__global__ __launch_bounds__(256) void normtv(
    unsigned short* __restrict__ qkv, unsigned short* __restrict__ vTg,
    const float* __restrict__ cosb, const float* __restrict__ sinb,
    const float* __restrict__ knw) {
  const int bid = blockIdx.x;
  const int tid = threadIdx.x;
  if (bid < 4096) {
    const int sub = tid >> 7, d = tid & 127;
    const int j = bid * 2 + sub;            // 0..8191
    const int t = j >> 2, kh = j & 3;
    size_t addr = (size_t)t * STRQKV + KOFF + kh * HD + d;
    float x = bf2f(qkv[addr]);
    float ss = x * x;
#pragma unroll
    for (int mk = 1; mk < 64; mk <<= 1) ss += __shfl_xor(ss, mk, 64);
    __shared__ float red[4];
    __shared__ float xs[256];
    if ((tid & 63) == 0) red[tid >> 6] = ss;
    __syncthreads();
    float rstd = rsqrtf((red[sub * 2] + red[sub * 2 + 1]) * (1.0f / 128.0f) + 1e-6f);
    float xn = x * rstd * knw[d];
    xs[tid] = xn;
    __syncthreads();
    float other = (d < 64) ? -xs[sub * 128 + d + 64] : xs[sub * 128 + d - 64];
    qkv[addr] = f2bf(xn * cosb[(size_t)t * HD + d] + other * sinb[(size_t)t * HD + d]);
    return;
  }
  const int lb = bid - 4096;                 // 0..1023
  const int tb = (lb & 63) * 32, db = ((lb >> 6) & 3) * 32, kvh = lb >> 8;
  __shared__ unsigned short tile[32][33];
  const int tx = tid & 31, ty = tid >> 5;
#pragma unroll
  for (int i = 0; i < 32; i += 8)
    tile[ty + i][tx] = qkv[(size_t)(tb + ty + i) * STRQKV + VOFF + kvh * HD + db + tx];
  __syncthreads();
#pragma unroll
  for (int i = 0; i < 32; i += 8)
    vTg[((size_t)kvh * HD + db + ty + i) * T_SEQ + tb + tx] = tile[tx][ty + i];
}

// ---------------- GEMM (BK=64): BMxBN tile, 8 waves (4x2), 2-buffer staging ----------------
// Chunk-XOR involution (ch ^= row&7) on both staging source and ds_read side:
// conflict-free (measured SQ_LDS_BANK_CONFLICT = 0). Half the barriers of BK=32.
// QKV: BM=128,BN=160 (512 blocks = 2/CU). O-proj: BM=64,BN=128 (512 = 2/CU —
// 1 block/CU exposes every barrier drain; 2/CU lets blocks cover each other).
template <int BM, int BN, typename OT>
__global__ __launch_bounds__(512) void gemm_bt64(const unsigned short* __restrict__ A,
                                                 const unsigned short* __restrict__ B,
                                                 OT* __restrict__ C, int M, int N, int K) {
  constexpr int NB = BN / 32;                 // col frags per wave
  constexpr int WROWS = BM / 4;               // rows per row-wave
  constexpr int NA = WROWS / 16;              // row frags per wave
  constexpr int ACH = BM * 8;                 // A 16B-chunks per tile
  constexpr int BCH = BN * 8;                 // B 16B-chunks per tile
  __shared__ unsigned short As[2][BM * 64];
  __shared__ unsigned short Bs[2][BN * 64];
  const int tid = threadIdx.x;
  const int wave = tid >> 6, lane = tid & 63;
  const int wr = wave >> 1, wc = wave & 1;
  const int g = lane >> 4, lr = lane & 15;
  const int row0 = blockIdx.y * BM, col0 = blockIdx.x * BN;

  auto stage = [&](int buf, int k0) {
#pragma unroll
    for (int i = 0; i < (ACH + 511) / 512; ++i) {
      int ci = i * 512 + tid;
      if (ci < ACH) {
        int row = ci >> 3, ch = (ci & 7) ^ (row & 7);
        gload16(A + (size_t)(row0 + row) * K + k0 + ch * 8, &As[buf][ci * 8]);
      }
    }
#pragma unroll
    for (int i = 0; i < (BCH + 511) / 512; ++i) {
      int ci = i * 512 + tid;
      if (ci < BCH) {
        int row = ci >> 3, ch = (ci & 7) ^ (row & 7);
        gload16(B + (size_t)(col0 + row) * K + k0 + ch * 8, &Bs[buf][ci * 8]);
      }
    }
  };

  f32x4 acc[NA][NB] = {};

  stage(0, 0);
  __syncthreads();
  int cur = 0;
  for (int k0 = 0; k0 < K; k0 += 64) {
    if (k0 + 64 < K) stage(cur ^ 1, k0 + 64);

#pragma unroll
    for (int kk = 0; kk < 2; ++kk) {
      bf16x8 af[NA], bfr[NB];
#pragma unroll
      for (int m = 0; m < NA; ++m) {
        int row = wr * WROWS + m * 16 + lr;
        af[m] = *(const bf16x8*)(&As[cur][row * 64 + (((kk * 4 + g) ^ (row & 7)) * 8)]);
      }
#pragma unroll
      for (int n = 0; n < NB; ++n) {
        int row = wc * (BN / 2) + n * 16 + lr;
        bfr[n] = *(const bf16x8*)(&Bs[cur][row * 64 + (((kk * 4 + g) ^ (row & 7)) * 8)]);
      }
      __builtin_amdgcn_s_setprio(1);
#pragma unroll
      for (int m = 0; m < NA; ++m)
#pragma unroll
        for (int n = 0; n < NB; ++n)
          acc[m][n] = mfma16(af[m], bfr[n], acc[m][n]);
      __builtin_amdgcn_s_setprio(0);
    }

    __syncthreads();
    cur ^= 1;
  }

#pragma unroll
  for (int m = 0; m < NA; ++m)
#pragma unroll
    for (int n = 0; n < NB; ++n)
#pragma unroll
      for (int r = 0; r < 4; ++r) {
        int row = row0 + wr * WROWS + m * 16 + g * 4 + r;
        int col = col0 + wc * (BN / 2) + n * 16 + lr;
        float v = acc[m][n][r];
        if constexpr (sizeof(OT) == 2) C[(size_t)row * N + col] = f2bf(v);
        else                            C[(size_t)row * N + col] = v;
      }
}

// ---------------- Flash attention + gate (Q norm/rope fused) — R18-proven ----------------
// 256 blocks x 8 waves; block = 2 HEADS (same kvh) x 64 q-rows; wave = 16 rows
// of one head. KVBLK=64, 2 buffers, stage(next)-before-compute(cur),
// ONE __syncthreads per tile. No-max exp2 softmax (RMSNorm bounds |logit|).
__global__ __launch_bounds__(512) void attn_kernel(
    const unsigned short* __restrict__ qkv, const unsigned short* __restrict__ vTg,
    const int* __restrict__ seg,
    const float* __restrict__ cosb, const float* __restrict__ sinb,
    const float* __restrict__ qnw,
    unsigned short* __restrict__ attnb) {
  const int bid = blockIdx.x;
  const int hp = bid & 7;                 // head-pair id: kvh = hp>>1, half = hp&1
  const int j = bid >> 3;                 // 0..31
  const int qb = (j < 16) ? j : 47 - j;   // co-resident pairing: qb + (31-qb)
  const int kvh = hp >> 1;
  const int tid = threadIdx.x;
  const int wave = tid >> 6, lane = tid & 63;
  const int g = lane >> 4, lr = lane & 15;
  const int h = kvh * 4 + (hp & 1) * 2 + (wave >> 2);  // this wave's q-head
  const int qrow0 = qb * 64 + (wave & 3) * 16;

  __shared__ unsigned short Ks[2][64 * 128];   // 32 KB
  __shared__ unsigned short Vt[2][128 * 64];   // 32 KB
  __shared__ unsigned short Plds[8][16][64];   // 16 KB (XOR col swizzle, no pad)

  const unsigned short* Kbase = qkv + KOFF + kvh * HD;         // row stride STRQKV
  const unsigned short* Vbase = vTg + (size_t)kvh * HD * T_SEQ;

  auto stage = [&](int buf, int kv0) {
#pragma unroll
    for (int i = 0; i < 2; ++i) {
      int row = i * 32 + (tid >> 4);            // K rows 0..63
      int c16 = (tid & 15) ^ (row & 7);
      gload16(Kbase + (size_t)(kv0 + row) * STRQKV + c16 * 8, &Ks[buf][i * 4096 + tid * 8]);
    }
#pragma unroll
    for (int i = 0; i < 2; ++i) {
      int row = i * 64 + (tid >> 3);            // V rows (d) 0..127
      int c16 = (tid & 7) ^ (row & 7);
      gload16(Vbase + (size_t)row * T_SEQ + kv0 + c16 * 8, &Vt[buf][i * 4096 + tid * 8]);
    }
  };

  const int ntiles = qb + 1;                   // 64-wide tiles
  const int segB = seg[qb * 64];
  int t_begin = 0;
  while (t_begin < ntiles - 1 && seg[t_begin * 64 + 63] < segB) ++t_begin;

  stage(0, t_begin * 64);

  // ---- fused Q RMSNorm + RoPE + scale (overlaps staging latency) ----
  const int t0 = qrow0 + lr;
  float xn[4][8];
  {
    float ssl = 0.f;
#pragma unroll
    for (int c = 0; c < 4; ++c) {
      bf16x8 tq = *(const bf16x8*)(qkv + (size_t)t0 * STRQKV + h * 256 + c * 32 + g * 8);
#pragma unroll
      for (int i = 0; i < 8; ++i) {
        float x = bf2f((unsigned short)tq[i]);
        xn[c][i] = x;
        ssl += x * x;
      }
    }
    ssl += __shfl_xor(ssl, 16, 64);
    ssl += __shfl_xor(ssl, 32, 64);
    float rstd = rsqrtf(ssl * (1.0f / 128.0f) + 1e-6f);
#pragma unroll
    for (int c = 0; c < 4; ++c)
#pragma unroll
      for (int i = 0; i < 8; ++i)
        xn[c][i] *= rstd * qnw[c * 32 + g * 8 + i];
  }
  bf16x8 qf[4];
#pragma unroll
  for (int c = 0; c < 4; ++c)
#pragma unroll
    for (int i = 0; i < 8; ++i) {
      int d = c * 32 + g * 8 + i;
      float rot = (c < 2) ? -xn[c + 2][i] : xn[c - 2][i];
      float ov = xn[c][i] * cosb[(size_t)t0 * HD + d] + rot * sinb[(size_t)t0 * HD + d];
      qf[c][i] = (short)f2bf(ov * (ATT_SCALE * LOG2E));   // log2-domain logits
    }

  bf16x8 vones;
#pragma unroll
  for (int i = 0; i < 8; ++i) vones[i] = (short)0x3F80;  // bf16 1.0

  int myrow[4], myseg[4];
#pragma unroll
  for (int r = 0; r < 4; ++r) {
    myrow[r] = qrow0 + g * 4 + r;
    myseg[r] = seg[myrow[r]];
  }
  const int seg_lo = seg[qrow0];
  const int seg_hi = seg[qrow0 + 15];

  f32x4 lacc = {};
  f32x4 oacc[8] = {};

  __syncthreads();  // first tile staged (drain)
  int cur = 0;
  for (int t = t_begin; t < ntiles; ++t) {
    const int kv0 = t * 64;
    if (t + 1 < ntiles) stage(cur ^ 1, kv0 + 64);  // overlaps compute below

    if (kv0 < qrow0 + 16 && seg[kv0 + 63] >= seg_lo) {  // wave-level causal/seg skip
      const unsigned short* ks = Ks[cur];
      const unsigned short* vt = Vt[cur];

      // ---- S = Q K^T : 16 x 64 (log2-domain) ----
      f32x4 sacc[4] = {};
      __builtin_amdgcn_s_setprio(1);
#pragma unroll
      for (int cc = 0; cc < 4; ++cc)
#pragma unroll
        for (int c = 0; c < 4; ++c) {
          int row = cc * 16 + lr;
          bf16x8 kf = *(const bf16x8*)(&ks[row * 128 + (((c * 4 + g) ^ (row & 7)) * 8)]);
          sacc[cc] = mfma16(qf[c], kf, sacc[cc]);
        }
      __builtin_amdgcn_s_setprio(0);

      // ---- P = exp2(S); Plds col' = col ^ ((row&3)<<4) ----
      const bool full = (kv0 + 64 <= qrow0) && (seg[kv0] == seg_hi);
      if (full) {
#pragma unroll
        for (int cc = 0; cc < 4; ++cc)
#pragma unroll
          for (int r = 0; r < 4; ++r)
            Plds[wave][g * 4 + r][((cc ^ r) * 16) + lr] = f2bf(exp2f(sacc[cc][r]));
      } else {
#pragma unroll
        for (int cc = 0; cc < 4; ++cc) {
          int kvi = kv0 + cc * 16 + lr;
          int ksg = seg[kvi];
#pragma unroll
          for (int r = 0; r < 4; ++r) {
            bool ok = (kvi <= myrow[r]) && (ksg == myseg[r]);
            float p = exp2f(sacc[cc][r]);
            Plds[wave][g * 4 + r][((cc ^ r) * 16) + lr] = f2bf(ok ? p : 0.0f);
          }
        }
      }

      // ---- PV: O += P[16x64] * V^T ; row-sum via ones-vector MFMA ----
      bf16x8 pf0 = *(const bf16x8*)(&Plds[wave][lr][(g * 8) ^ ((lr & 3) << 4)]);
      bf16x8 pf1 = *(const bf16x8*)(&Plds[wave][lr][(32 + g * 8) ^ ((lr & 3) << 4)]);
      __builtin_amdgcn_s_setprio(1);
#pragma unroll
      for (int n = 0; n < 8; ++n) {
        int row = n * 16 + lr;
        bf16x8 vf0 = *(const bf16x8*)(&vt[row * 64 + ((g ^ (row & 7)) * 8)]);
        oacc[n] = mfma16(pf0, vf0, oacc[n]);
        bf16x8 vf1 = *(const bf16x8*)(&vt[row * 64 + (((4 + g) ^ (row & 7)) * 8)]);
        oacc[n] = mfma16(pf1, vf1, oacc[n]);
      }
      lacc = mfma16(pf0, vones, lacc);
      lacc = mfma16(pf1, vones, lacc);
      __builtin_amdgcn_s_setprio(0);
    }

    __syncthreads();  // prefetch drained + all waves done with buf cur
    cur ^= 1;
  }

  // epilogue: normalize, sigmoid-gate, store bf16
#pragma unroll
  for (int n = 0; n < 8; ++n)
#pragma unroll
    for (int r = 0; r < 4; ++r) {
      int row = myrow[r];
      int d = n * 16 + lr;
      float o = oacc[n][r] / lacc[r];
      float gv = bf2f(qkv[(size_t)row * STRQKV + h * 256 + 128 + d]);
      float gate = 1.0f / (1.0f + __expf(-gv));
      attnb[(size_t)row * (NH * HD) + h * HD + d] = f2bf(o * gate);
    }
}

extern "C" void kernel_launch(void* const* d_in, const int* in_sizes, int n_in,
                              void* d_out, int out_size, void* d_ws, size_t ws_size,
                              hipStream_t stream) {
  const float* hidden = (const float*)d_in[0];
  const float* cosb   = (const float*)d_in[1];
  const float* sinb   = (const float*)d_in[2];
  const int*   seg    = (const int*)d_in[3];
  // d_in[4] = position_ids (arange; causal handled by index arithmetic)
  const float* wq     = (const float*)d_in[5];
  const float* wk     = (const float*)d_in[6];
  const float* wv     = (const float*)d_in[7];
  const float* wo     = (const float*)d_in[8];
  const float* qnw    = (const float*)d_in[9];
  const float* knw    = (const float*)d_in[10];
  float* out = (float*)d_out;

  // Workspace layout (liveness-aliased):
  //   [0,8)    Xb (hidden bf16)   -> dead after QKV GEMM -> Attnb
  //   [8,28)   Wqkvt [5120][2048] -> dead after QKV GEMM -> VT [16,18)
  //   [28,48)  Cqkv [2048][5120]  (q|gate|k|v; k normed/roped in place)
  //   [48,56)  Wot (only if ws_size >= 56MB; else Wot aliases [8,16) post-GEMM)
  char* ws = (char*)d_ws;
  const size_t MB = (size_t)1 << 20;
  const bool big = ws_size >= 56 * MB;
  unsigned short* Xb    = (unsigned short*)(ws + 0 * MB);
  unsigned short* Attnb = (unsigned short*)(ws + 0 * MB);
  unsigned short* Wqkvt = (unsigned short*)(ws + 8 * MB);
  unsigned short* VT    = (unsigned short*)(ws + 16 * MB);
  unsigned short* Cqkv  = (unsigned short*)(ws + 28 * MB);
  unsigned short* Wot   = (unsigned short*)(big ? (ws + 48 * MB) : (ws + 8 * MB));

  prep<<<big ? 18432 : 14336, 256, 0, stream>>>(hidden, wq, wk, wv, wo, Xb, Wqkvt, Wot);

  gemm_bt64<128, 160, unsigned short><<<dim3(STRQKV / 160, T_SEQ / 128), 512, 0, stream>>>(Xb, Wqkvt, Cqkv, T_SEQ, STRQKV, DMODEL);

  if (!big)
    transpose_wo<<<dim3(DMODEL / 32, DMODEL / 32), 256, 0, stream>>>(wo, Wot);

  normtv<<<5120, 256, 0, stream>>>(Cqkv, VT, cosb, sinb, knw);

  attn_kernel<<<256, 512, 0, stream>>>(Cqkv, VT, seg, cosb, sinb, qnw, Attnb);

  gemm_bt64<64, 128, float><<<dim3(DMODEL / 128, T_SEQ / 64), 512, 0, stream>>>(Attnb, Wot, out, T_SEQ, DMODEL, DMODEL);
}

// Round 22
// 134.365 us; speedup vs baseline: 1.1046x; 1.0149x over previous
//
#include <hip/hip_runtime.h>

typedef __attribute__((ext_vector_type(8))) short bf16x8;
typedef __attribute__((ext_vector_type(4))) float f32x4;
typedef __attribute__((ext_vector_type(4))) unsigned short us4;

#define T_SEQ 2048
#define DMODEL 2048
#define NH 16
#define NKV 4
#define HD 128
#define STRQKV 5120   /* NH*HD*2 + 2*NKV*HD : fused QKV output row stride */
#define KOFF 4096
#define VOFF 4608
#define ATT_SCALE 0.08838834764831845f
#define LOG2E 1.4426950408889634f

__device__ __forceinline__ float bf2f(unsigned short u) {
  union { unsigned int u; float f; } v; v.u = ((unsigned int)u) << 16; return v.f;
}
__device__ __forceinline__ unsigned short f2bf(float f) {
  union { float f; unsigned int u; } v; v.f = f;
  unsigned int u = v.u;
  return (unsigned short)((u + 0x7fffu + ((u >> 16) & 1u)) >> 16);
}
__device__ __forceinline__ f32x4 mfma16(bf16x8 a, bf16x8 b, f32x4 c) {
  return __builtin_amdgcn_mfma_f32_16x16x32_bf16(a, b, c, 0, 0, 0);
}
__device__ __forceinline__ void gload16(const void* g, void* l) {
  __builtin_amdgcn_global_load_lds(
      (const __attribute__((address_space(1))) unsigned int*)g,
      (__attribute__((address_space(3))) unsigned int*)l, 16, 0, 0);
}

// ---------------- fused prologue: convert hidden + transpose wq/wk/wv(/wo) ----------------
__global__ __launch_bounds__(256) void prep(
    const float* __restrict__ hidden, const float* __restrict__ wq,
    const float* __restrict__ wk, const float* __restrict__ wv,
    const float* __restrict__ wo,
    unsigned short* __restrict__ Xb, unsigned short* __restrict__ Wqkvt,
    unsigned short* __restrict__ Wot) {
  const int bid = blockIdx.x;
  const int tid = threadIdx.x;
  if (bid < 4096) {  // fp32 -> bf16 convert, float4/thread
    int i = bid * 256 + tid;
    float4 v = ((const float4*)hidden)[i];
    us4 o; o.x = f2bf(v.x); o.y = f2bf(v.y); o.z = f2bf(v.z); o.w = f2bf(v.w);
    ((us4*)Xb)[i] = o;
    return;
  }
  const float* in; unsigned short* out; int N, lb;
  if (bid < 12288)      { in = wq; out = Wqkvt;                          N = 4096; lb = bid - 4096; }
  else if (bid < 13312) { in = wk; out = Wqkvt + (size_t)KOFF * DMODEL;  N = 512;  lb = bid - 12288; }
  else if (bid < 14336) { in = wv; out = Wqkvt + (size_t)VOFF * DMODEL;  N = 512;  lb = bid - 13312; }
  else                  { in = wo; out = Wot;                            N = 2048; lb = bid - 14336; }
  const int ntb = N >> 5;
  const int nb = (lb % ntb) * 32, kb = (lb / ntb) * 32;
  __shared__ unsigned short tile[32][33];
  const int tx = tid & 31, ty = tid >> 5;
#pragma unroll
  for (int i = 0; i < 32; i += 8)
    tile[ty + i][tx] = f2bf(in[(size_t)(kb + ty + i) * N + nb + tx]);
  __syncthreads();
#pragma unroll
  for (int i = 0; i < 32; i += 8)
    out[(size_t)(nb + ty + i) * DMODEL + kb + tx] = tile[tx][ty + i];
}

// fallback wo transpose (when ws too small to host Wot separately pre-GEMM)
__global__ __launch_bounds__(256) void transpose_wo(
    const float* __restrict__ in, unsigned short* __restrict__ out) {
  __shared__ unsigned short tile[32][33];
  int nb = blockIdx.x * 32, kb = blockIdx.y * 32;
  int tx = threadIdx.x & 31, ty = threadIdx.x >> 5;
#pragma unroll
  for (int i = 0; i < 32; i += 8)
    tile[ty + i][tx] = f2bf(in[(size_t)(kb + ty + i) * DMODEL + nb + tx]);
  __syncthreads();
#pragma unroll
  for (int i = 0; i < 32; i += 8)
    out[(size_t)(nb + ty + i) * DMODEL + kb + tx] = tile[tx][ty + i];
}

// ---------------- fused K-RMSNorm+RoPE (in place) + V transpose ----------------
__global__ __launch_bounds__(256) void normtv(
    unsigned short* __restrict__ qkv, unsigned short* __restrict__ vTg,
    const float* __restrict__ cosb, const float* __restrict__ sinb,
    const float* __restrict__ knw) {
  const int bid = blockIdx.x;
  const int tid = threadIdx.x;
  if (bid < 4096) {
    const int sub = tid >> 7, d = tid & 127;
    const int j = bid * 2 + sub;            // 0..8191
    const int t = j >> 2, kh = j & 3;
    size_t addr = (size_t)t * STRQKV + KOFF + kh * HD + d;
    float x = bf2f(qkv[addr]);
    float ss = x * x;
#pragma unroll
    for (int mk = 1; mk < 64; mk <<= 1) ss += __shfl_xor(ss, mk, 64);
    __shared__ float red[4];
    __shared__ float xs[256];
    if ((tid & 63) == 0) red[tid >> 6] = ss;
    __syncthreads();
    float rstd = rsqrtf((red[sub * 2] + red[sub * 2 + 1]) * (1.0f / 128.0f) + 1e-6f);
    float xn = x * rstd * knw[d];
    xs[tid] = xn;
    __syncthreads();
    float other = (d < 64) ? -xs[sub * 128 + d + 64] : xs[sub * 128 + d - 64];
    qkv[addr] = f2bf(xn * cosb[(size_t)t * HD + d] + other * sinb[(size_t)t * HD + d]);
    return;
  }
  const int lb = bid - 4096;                 // 0..1023
  const int tb = (lb & 63) * 32, db = ((lb >> 6) & 3) * 32, kvh = lb >> 8;
  __shared__ unsigned short tile[32][33];
  const int tx = tid & 31, ty = tid >> 5;
#pragma unroll
  for (int i = 0; i < 32; i += 8)
    tile[ty + i][tx] = qkv[(size_t)(tb + ty + i) * STRQKV + VOFF + kvh * HD + db + tx];
  __syncthreads();
#pragma unroll
  for (int i = 0; i < 32; i += 8)
    vTg[((size_t)kvh * HD + db + ty + i) * T_SEQ + tb + tx] = tile[tx][ty + i];
}

// ---------------- GEMM (BK=64): BMxBN tile, 8 waves (4x2), 2-buffer staging ----------------
// Chunk-XOR involution (ch ^= row&7) on both staging source and ds_read side:
// conflict-free (measured SQ_LDS_BANK_CONFLICT = 0). Half the barriers of BK=32.
// QKV: BM=128,BN=160 (512 blocks = 2/CU). O-proj: BM=64,BN=128 (512 = 2/CU).
template <int BM, int BN, typename OT>
__global__ __launch_bounds__(512) void gemm_bt64(const unsigned short* __restrict__ A,
                                                 const unsigned short* __restrict__ B,
                                                 OT* __restrict__ C, int M, int N, int K) {
  constexpr int NB = BN / 32;                 // col frags per wave
  constexpr int WROWS = BM / 4;               // rows per row-wave
  constexpr int NA = WROWS / 16;              // row frags per wave
  constexpr int ACH = BM * 8;                 // A 16B-chunks per tile
  constexpr int BCH = BN * 8;                 // B 16B-chunks per tile
  __shared__ unsigned short As[2][BM * 64];
  __shared__ unsigned short Bs[2][BN * 64];
  const int tid = threadIdx.x;
  const int wave = tid >> 6, lane = tid & 63;
  const int wr = wave >> 1, wc = wave & 1;
  const int g = lane >> 4, lr = lane & 15;
  const int row0 = blockIdx.y * BM, col0 = blockIdx.x * BN;

  auto stage = [&](int buf, int k0) {
#pragma unroll
    for (int i = 0; i < (ACH + 511) / 512; ++i) {
      int ci = i * 512 + tid;
      if (ci < ACH) {
        int row = ci >> 3, ch = (ci & 7) ^ (row & 7);
        gload16(A + (size_t)(row0 + row) * K + k0 + ch * 8, &As[buf][ci * 8]);
      }
    }
#pragma unroll
    for (int i = 0; i < (BCH + 511) / 512; ++i) {
      int ci = i * 512 + tid;
      if (ci < BCH) {
        int row = ci >> 3, ch = (ci & 7) ^ (row & 7);
        gload16(B + (size_t)(col0 + row) * K + k0 + ch * 8, &Bs[buf][ci * 8]);
      }
    }
  };

  f32x4 acc[NA][NB] = {};

  stage(0, 0);
  __syncthreads();
  int cur = 0;
  for (int k0 = 0; k0 < K; k0 += 64) {
    if (k0 + 64 < K) stage(cur ^ 1, k0 + 64);

#pragma unroll
    for (int kk = 0; kk < 2; ++kk) {
      bf16x8 af[NA], bfr[NB];
#pragma unroll
      for (int m = 0; m < NA; ++m) {
        int row = wr * WROWS + m * 16 + lr;
        af[m] = *(const bf16x8*)(&As[cur][row * 64 + (((kk * 4 + g) ^ (row & 7)) * 8)]);
      }
#pragma unroll
      for (int n = 0; n < NB; ++n) {
        int row = wc * (BN / 2) + n * 16 + lr;
        bfr[n] = *(const bf16x8*)(&Bs[cur][row * 64 + (((kk * 4 + g) ^ (row & 7)) * 8)]);
      }
      __builtin_amdgcn_s_setprio(1);
#pragma unroll
      for (int m = 0; m < NA; ++m)
#pragma unroll
        for (int n = 0; n < NB; ++n)
          acc[m][n] = mfma16(af[m], bfr[n], acc[m][n]);
      __builtin_amdgcn_s_setprio(0);
    }

    __syncthreads();
    cur ^= 1;
  }

#pragma unroll
  for (int m = 0; m < NA; ++m)
#pragma unroll
    for (int n = 0; n < NB; ++n)
#pragma unroll
      for (int r = 0; r < 4; ++r) {
        int row = row0 + wr * WROWS + m * 16 + g * 4 + r;
        int col = col0 + wc * (BN / 2) + n * 16 + lr;
        float v = acc[m][n][r];
        if constexpr (sizeof(OT) == 2) C[(size_t)row * N + col] = f2bf(v);
        else                            C[(size_t)row * N + col] = v;
      }
}

// ---------------- Flash attention + gate (Q norm/rope fused) ----------------
// 512 blocks x 4 waves (256 thr); block = 64 q-rows x 1 head; co-resident
// pairing qb=(j<16)?j:47-j -> blocks (bid,bid+256) share a CU and their work
// sums to 33 tile-units (balanced makespan; 2 blocks/CU, LDS 72KB). KVBLK=64,
// 2 buffers, stage-before-compute, ONE __syncthreads/tile, no-max exp2 softmax.
__global__ __launch_bounds__(256) void attn_kernel(
    const unsigned short* __restrict__ qkv, const unsigned short* __restrict__ vTg,
    const int* __restrict__ seg,
    const float* __restrict__ cosb, const float* __restrict__ sinb,
    const float* __restrict__ qnw,
    unsigned short* __restrict__ attnb) {
  const int bid = blockIdx.x;
  const int h = bid & 15;
  const int j = bid >> 4;                 // 0..31
  const int qb = (j < 16) ? j : 47 - j;   // co-resident pairing: qb + (31-qb)
  const int kvh = h >> 2;
  const int tid = threadIdx.x;
  const int wave = tid >> 6, lane = tid & 63;
  const int g = lane >> 4, lr = lane & 15;
  const int qrow0 = qb * 64 + wave * 16;

  __shared__ unsigned short Ks[2][64 * 128];   // 32 KB
  __shared__ unsigned short Vt[2][128 * 64];   // 32 KB
  __shared__ unsigned short Plds[4][16][64];   // 8 KB (XOR col swizzle, no pad)

  const unsigned short* Kbase = qkv + KOFF + kvh * HD;         // row stride STRQKV
  const unsigned short* Vbase = vTg + (size_t)kvh * HD * T_SEQ;

  // 256 threads: K tile = 64 rows x 16 chunks = 1024 chunks (4 issues);
  //              V tile = 128 rows x 8 chunks = 1024 chunks (4 issues).
  auto stage = [&](int buf, int kv0) {
#pragma unroll
    for (int i = 0; i < 4; ++i) {
      int ci = i * 256 + tid;
      int row = ci >> 4, c16 = (ci & 15) ^ (row & 7);
      gload16(Kbase + (size_t)(kv0 + row) * STRQKV + c16 * 8, &Ks[buf][ci * 8]);
    }
#pragma unroll
    for (int i = 0; i < 4; ++i) {
      int ci = i * 256 + tid;
      int row = ci >> 3, ch = (ci & 7) ^ (row & 7);
      gload16(Vbase + (size_t)row * T_SEQ + kv0 + ch * 8, &Vt[buf][ci * 8]);
    }
  };

  const int ntiles = qb + 1;                   // 64-wide tiles
  const int segB = seg[qb * 64];
  int t_begin = 0;
  while (t_begin < ntiles - 1 && seg[t_begin * 64 + 63] < segB) ++t_begin;

  stage(0, t_begin * 64);

  // ---- fused Q RMSNorm + RoPE + scale (overlaps staging latency) ----
  const int t0 = qrow0 + lr;
  float xn[4][8];
  {
    float ssl = 0.f;
#pragma unroll
    for (int c = 0; c < 4; ++c) {
      bf16x8 tq = *(const bf16x8*)(qkv + (size_t)t0 * STRQKV + h * 256 + c * 32 + g * 8);
#pragma unroll
      for (int i = 0; i < 8; ++i) {
        float x = bf2f((unsigned short)tq[i]);
        xn[c][i] = x;
        ssl += x * x;
      }
    }
    ssl += __shfl_xor(ssl, 16, 64);
    ssl += __shfl_xor(ssl, 32, 64);
    float rstd = rsqrtf(ssl * (1.0f / 128.0f) + 1e-6f);
#pragma unroll
    for (int c = 0; c < 4; ++c)
#pragma unroll
      for (int i = 0; i < 8; ++i)
        xn[c][i] *= rstd * qnw[c * 32 + g * 8 + i];
  }
  bf16x8 qf[4];
#pragma unroll
  for (int c = 0; c < 4; ++c)
#pragma unroll
    for (int i = 0; i < 8; ++i) {
      int d = c * 32 + g * 8 + i;
      float rot = (c < 2) ? -xn[c + 2][i] : xn[c - 2][i];
      float ov = xn[c][i] * cosb[(size_t)t0 * HD + d] + rot * sinb[(size_t)t0 * HD + d];
      qf[c][i] = (short)f2bf(ov * (ATT_SCALE * LOG2E));   // log2-domain logits
    }

  bf16x8 vones;
#pragma unroll
  for (int i = 0; i < 8; ++i) vones[i] = (short)0x3F80;  // bf16 1.0

  int myrow[4], myseg[4];
#pragma unroll
  for (int r = 0; r < 4; ++r) {
    myrow[r] = qrow0 + g * 4 + r;
    myseg[r] = seg[myrow[r]];
  }
  const int seg_lo = seg[qrow0];
  const int seg_hi = seg[qrow0 + 15];

  f32x4 lacc = {};
  f32x4 oacc[8] = {};

  __syncthreads();  // first tile staged (drain)
  int cur = 0;
  for (int t = t_begin; t < ntiles; ++t) {
    const int kv0 = t * 64;
    if (t + 1 < ntiles) stage(cur ^ 1, kv0 + 64);  // overlaps compute below

    if (kv0 < qrow0 + 16 && seg[kv0 + 63] >= seg_lo) {  // wave-level causal/seg skip
      const unsigned short* ks = Ks[cur];
      const unsigned short* vt = Vt[cur];

      // ---- S = Q K^T : 16 x 64 (log2-domain) ----
      f32x4 sacc[4] = {};
      __builtin_amdgcn_s_setprio(1);
#pragma unroll
      for (int cc = 0; cc < 4; ++cc)
#pragma unroll
        for (int c = 0; c < 4; ++c) {
          int row = cc * 16 + lr;
          bf16x8 kf = *(const bf16x8*)(&ks[row * 128 + (((c * 4 + g) ^ (row & 7)) * 8)]);
          sacc[cc] = mfma16(qf[c], kf, sacc[cc]);
        }
      __builtin_amdgcn_s_setprio(0);

      // ---- P = exp2(S); Plds col' = col ^ ((row&3)<<4) ----
      const bool full = (kv0 + 64 <= qrow0) && (seg[kv0] == seg_hi);
      if (full) {
#pragma unroll
        for (int cc = 0; cc < 4; ++cc)
#pragma unroll
          for (int r = 0; r < 4; ++r)
            Plds[wave][g * 4 + r][((cc ^ r) * 16) + lr] = f2bf(exp2f(sacc[cc][r]));
      } else {
#pragma unroll
        for (int cc = 0; cc < 4; ++cc) {
          int kvi = kv0 + cc * 16 + lr;
          int ksg = seg[kvi];
#pragma unroll
          for (int r = 0; r < 4; ++r) {
            bool ok = (kvi <= myrow[r]) && (ksg == myseg[r]);
            float p = exp2f(sacc[cc][r]);
            Plds[wave][g * 4 + r][((cc ^ r) * 16) + lr] = f2bf(ok ? p : 0.0f);
          }
        }
      }

      // ---- PV: O += P[16x64] * V^T ; row-sum via ones-vector MFMA ----
      bf16x8 pf0 = *(const bf16x8*)(&Plds[wave][lr][(g * 8) ^ ((lr & 3) << 4)]);
      bf16x8 pf1 = *(const bf16x8*)(&Plds[wave][lr][(32 + g * 8) ^ ((lr & 3) << 4)]);
      __builtin_amdgcn_s_setprio(1);
#pragma unroll
      for (int n = 0; n < 8; ++n) {
        int row = n * 16 + lr;
        bf16x8 vf0 = *(const bf16x8*)(&vt[row * 64 + ((g ^ (row & 7)) * 8)]);
        oacc[n] = mfma16(pf0, vf0, oacc[n]);
        bf16x8 vf1 = *(const bf16x8*)(&vt[row * 64 + (((4 + g) ^ (row & 7)) * 8)]);
        oacc[n] = mfma16(pf1, vf1, oacc[n]);
      }
      lacc = mfma16(pf0, vones, lacc);
      lacc = mfma16(pf1, vones, lacc);
      __builtin_amdgcn_s_setprio(0);
    }

    __syncthreads();  // prefetch drained + all waves done with buf cur
    cur ^= 1;
  }

  // epilogue: normalize, sigmoid-gate, store bf16
#pragma unroll
  for (int n = 0; n < 8; ++n)
#pragma unroll
    for (int r = 0; r < 4; ++r) {
      int row = myrow[r];
      int d = n * 16 + lr;
      float o = oacc[n][r] / lacc[r];
      float gv = bf2f(qkv[(size_t)row * STRQKV + h * 256 + 128 + d]);
      float gate = 1.0f / (1.0f + __expf(-gv));
      attnb[(size_t)row * (NH * HD) + h * HD + d] = f2bf(o * gate);
    }
}

extern "C" void kernel_launch(void* const* d_in, const int* in_sizes, int n_in,
                              void* d_out, int out_size, void* d_ws, size_t ws_size,
                              hipStream_t stream) {
  const float* hidden = (const float*)d_in[0];
  const float* cosb   = (const float*)d_in[1];
  const float* sinb   = (const float*)d_in[2];
  const int*   seg    = (const int*)d_in[3];
  // d_in[4] = position_ids (arange; causal handled by index arithmetic)
  const float* wq     = (const float*)d_in[5];
  const float* wk     = (const float*)d_in[6];
  const float* wv     = (const float*)d_in[7];
  const float* wo     = (const float*)d_in[8];
  const float* qnw    = (const float*)d_in[9];
  const float* knw    = (const float*)d_in[10];
  float* out = (float*)d_out;

  // Workspace layout (liveness-aliased):
  //   [0,8)    Xb (hidden bf16)   -> dead after QKV GEMM -> Attnb
  //   [8,28)   Wqkvt [5120][2048] -> dead after QKV GEMM -> VT [16,18)
  //   [28,48)  Cqkv [2048][5120]  (q|gate|k|v; k normed/roped in place)
  //   [48,56)  Wot (only if ws_size >= 56MB; else Wot aliases [8,16) post-GEMM)
  char* ws = (char*)d_ws;
  const size_t MB = (size_t)1 << 20;
  const bool big = ws_size >= 56 * MB;
  unsigned short* Xb    = (unsigned short*)(ws + 0 * MB);
  unsigned short* Attnb = (unsigned short*)(ws + 0 * MB);
  unsigned short* Wqkvt = (unsigned short*)(ws + 8 * MB);
  unsigned short* VT    = (unsigned short*)(ws + 16 * MB);
  unsigned short* Cqkv  = (unsigned short*)(ws + 28 * MB);
  unsigned short* Wot   = (unsigned short*)(big ? (ws + 48 * MB) : (ws + 8 * MB));

  prep<<<big ? 18432 : 14336, 256, 0, stream>>>(hidden, wq, wk, wv, wo, Xb, Wqkvt, Wot);

  gemm_bt64<128, 160, unsigned short><<<dim3(STRQKV / 160, T_SEQ / 128), 512, 0, stream>>>(Xb, Wqkvt, Cqkv, T_SEQ, STRQKV, DMODEL);

  if (!big)
    transpose_wo<<<dim3(DMODEL / 32, DMODEL / 32), 256, 0, stream>>>(wo, Wot);

  normtv<<<5120, 256, 0, stream>>>(Cqkv, VT, cosb, sinb, knw);

  attn_kernel<<<512, 256, 0, stream>>>(Cqkv, VT, seg, cosb, sinb, qnw, Attnb);

  gemm_bt64<64, 128, float><<<dim3(DMODEL / 128, T_SEQ / 64), 512, 0, stream>>>(Attnb, Wot, out, T_SEQ, DMODEL, DMODEL);
}

// Round 23
// 133.893 us; speedup vs baseline: 1.1085x; 1.0035x over previous
//
#include <hip/hip_runtime.h>

typedef __attribute__((ext_vector_type(8))) short bf16x8;
typedef __attribute__((ext_vector_type(4))) float f32x4;
typedef __attribute__((ext_vector_type(4))) unsigned short us4;

#define T_SEQ 2048
#define DMODEL 2048
#define NH 16
#define NKV 4
#define HD 128
#define STRQKV 5120   /* NH*HD*2 + 2*NKV*HD : fused QKV output row stride */
#define KOFF 4096
#define VOFF 4608
#define ATT_SCALE 0.08838834764831845f
#define LOG2E 1.4426950408889634f

__device__ __forceinline__ float bf2f(unsigned short u) {
  union { unsigned int u; float f; } v; v.u = ((unsigned int)u) << 16; return v.f;
}
__device__ __forceinline__ unsigned short f2bf(float f) {
  union { float f; unsigned int u; } v; v.f = f;
  unsigned int u = v.u;
  return (unsigned short)((u + 0x7fffu + ((u >> 16) & 1u)) >> 16);
}
__device__ __forceinline__ f32x4 mfma16(bf16x8 a, bf16x8 b, f32x4 c) {
  return __builtin_amdgcn_mfma_f32_16x16x32_bf16(a, b, c, 0, 0, 0);
}
__device__ __forceinline__ void gload16(const void* g, void* l) {
  __builtin_amdgcn_global_load_lds(
      (const __attribute__((address_space(1))) unsigned int*)g,
      (__attribute__((address_space(3))) unsigned int*)l, 16, 0, 0);
}

// ---------------- fused prologue: convert hidden + transpose wq/wk/wv(/wo) ----------------
// Transposes use 64x64 tiles: float4 reads (256B/row) + ushort4 writes (128B/row).
// jobs: [0,4096) convert; [4096,6144) wq (32x64 tiles); +256 wk; +256 wv; +1024 wo
__global__ __launch_bounds__(256) void prep(
    const float* __restrict__ hidden, const float* __restrict__ wq,
    const float* __restrict__ wk, const float* __restrict__ wv,
    const float* __restrict__ wo,
    unsigned short* __restrict__ Xb, unsigned short* __restrict__ Wqkvt,
    unsigned short* __restrict__ Wot) {
  const int bid = blockIdx.x;
  const int tid = threadIdx.x;
  if (bid < 4096) {  // fp32 -> bf16 convert, float4/thread
    int i = bid * 256 + tid;
    float4 v = ((const float4*)hidden)[i];
    us4 o; o.x = f2bf(v.x); o.y = f2bf(v.y); o.z = f2bf(v.z); o.w = f2bf(v.w);
    ((us4*)Xb)[i] = o;
    return;
  }
  const float* in; unsigned short* out; int N, lb;
  if (bid < 6144)       { in = wq; out = Wqkvt;                          N = 4096; lb = bid - 4096; }
  else if (bid < 6400)  { in = wk; out = Wqkvt + (size_t)KOFF * DMODEL;  N = 512;  lb = bid - 6144; }
  else if (bid < 6656)  { in = wv; out = Wqkvt + (size_t)VOFF * DMODEL;  N = 512;  lb = bid - 6400; }
  else                  { in = wo; out = Wot;                            N = 2048; lb = bid - 6656; }
  const int ntb = N >> 6;
  const int nb = (lb % ntb) * 64, kb = (lb / ntb) * 64;
  __shared__ unsigned short tile[64][65];
#pragma unroll
  for (int it = 0; it < 4; ++it) {
    int idx = it * 256 + tid;
    int r = idx >> 4, c4 = (idx & 15) * 4;
    float4 v = *(const float4*)&in[(size_t)(kb + r) * N + nb + c4];
    tile[c4 + 0][r] = f2bf(v.x);
    tile[c4 + 1][r] = f2bf(v.y);
    tile[c4 + 2][r] = f2bf(v.z);
    tile[c4 + 3][r] = f2bf(v.w);
  }
  __syncthreads();
#pragma unroll
  for (int it = 0; it < 4; ++it) {
    int idx = it * 256 + tid;
    int j = idx >> 4, i4 = (idx & 15) * 4;
    us4 w;
    w.x = tile[j][i4 + 0];
    w.y = tile[j][i4 + 1];
    w.z = tile[j][i4 + 2];
    w.w = tile[j][i4 + 3];
    *(us4*)&out[(size_t)(nb + j) * DMODEL + kb + i4] = w;
  }
}

// fallback wo transpose (when ws too small to host Wot separately pre-GEMM)
__global__ __launch_bounds__(256) void transpose_wo(
    const float* __restrict__ in, unsigned short* __restrict__ out) {
  __shared__ unsigned short tile[32][33];
  int nb = blockIdx.x * 32, kb = blockIdx.y * 32;
  int tx = threadIdx.x & 31, ty = threadIdx.x >> 5;
#pragma unroll
  for (int i = 0; i < 32; i += 8)
    tile[ty + i][tx] = f2bf(in[(size_t)(kb + ty + i) * DMODEL + nb + tx]);
  __syncthreads();
#pragma unroll
  for (int i = 0; i < 32; i += 8)
    out[(size_t)(nb + ty + i) * DMODEL + kb + tx] = tile[tx][ty + i];
}

// ---------------- fused K-RMSNorm+RoPE (in place) + V transpose ----------------
__global__ __launch_bounds__(256) void normtv(
    unsigned short* __restrict__ qkv, unsigned short* __restrict__ vTg,
    const float* __restrict__ cosb, const float* __restrict__ sinb,
    const float* __restrict__ knw) {
  const int bid = blockIdx.x;
  const int tid = threadIdx.x;
  if (bid < 4096) {
    const int sub = tid >> 7, d = tid & 127;
    const int j = bid * 2 + sub;            // 0..8191
    const int t = j >> 2, kh = j & 3;
    size_t addr = (size_t)t * STRQKV + KOFF + kh * HD + d;
    float x = bf2f(qkv[addr]);
    float ss = x * x;
#pragma unroll
    for (int mk = 1; mk < 64; mk <<= 1) ss += __shfl_xor(ss, mk, 64);
    __shared__ float red[4];
    __shared__ float xs[256];
    if ((tid & 63) == 0) red[tid >> 6] = ss;
    __syncthreads();
    float rstd = rsqrtf((red[sub * 2] + red[sub * 2 + 1]) * (1.0f / 128.0f) + 1e-6f);
    float xn = x * rstd * knw[d];
    xs[tid] = xn;
    __syncthreads();
    float other = (d < 64) ? -xs[sub * 128 + d + 64] : xs[sub * 128 + d - 64];
    qkv[addr] = f2bf(xn * cosb[(size_t)t * HD + d] + other * sinb[(size_t)t * HD + d]);
    return;
  }
  const int lb = bid - 4096;                 // 0..1023
  const int tb = (lb & 63) * 32, db = ((lb >> 6) & 3) * 32, kvh = lb >> 8;
  __shared__ unsigned short tile[32][33];
  const int tx = tid & 31, ty = tid >> 5;
#pragma unroll
  for (int i = 0; i < 32; i += 8)
    tile[ty + i][tx] = qkv[(size_t)(tb + ty + i) * STRQKV + VOFF + kvh * HD + db + tx];
  __syncthreads();
#pragma unroll
  for (int i = 0; i < 32; i += 8)
    vTg[((size_t)kvh * HD + db + ty + i) * T_SEQ + tb + tx] = tile[tx][ty + i];
}

// ---------------- GEMM (BK=64): BMxBN tile, 8 waves (4x2), 2-buffer staging ----------------
// Chunk-XOR involution (ch ^= row&7) on both staging source and ds_read side:
// conflict-free (measured SQ_LDS_BANK_CONFLICT = 0). Half the barriers of BK=32.
// QKV: BM=128,BN=160 (512 blocks = 2/CU). O-proj: BM=64,BN=128 (512 = 2/CU).
template <int BM, int BN, typename OT>
__global__ __launch_bounds__(512) void gemm_bt64(const unsigned short* __restrict__ A,
                                                 const unsigned short* __restrict__ B,
                                                 OT* __restrict__ C, int M, int N, int K) {
  constexpr int NB = BN / 32;                 // col frags per wave
  constexpr int WROWS = BM / 4;               // rows per row-wave
  constexpr int NA = WROWS / 16;              // row frags per wave
  constexpr int ACH = BM * 8;                 // A 16B-chunks per tile
  constexpr int BCH = BN * 8;                 // B 16B-chunks per tile
  __shared__ unsigned short As[2][BM * 64];
  __shared__ unsigned short Bs[2][BN * 64];
  const int tid = threadIdx.x;
  const int wave = tid >> 6, lane = tid & 63;
  const int wr = wave >> 1, wc = wave & 1;
  const int g = lane >> 4, lr = lane & 15;
  const int row0 = blockIdx.y * BM, col0 = blockIdx.x * BN;

  auto stage = [&](int buf, int k0) {
#pragma unroll
    for (int i = 0; i < (ACH + 511) / 512; ++i) {
      int ci = i * 512 + tid;
      if (ci < ACH) {
        int row = ci >> 3, ch = (ci & 7) ^ (row & 7);
        gload16(A + (size_t)(row0 + row) * K + k0 + ch * 8, &As[buf][ci * 8]);
      }
    }
#pragma unroll
    for (int i = 0; i < (BCH + 511) / 512; ++i) {
      int ci = i * 512 + tid;
      if (ci < BCH) {
        int row = ci >> 3, ch = (ci & 7) ^ (row & 7);
        gload16(B + (size_t)(col0 + row) * K + k0 + ch * 8, &Bs[buf][ci * 8]);
      }
    }
  };

  f32x4 acc[NA][NB] = {};

  stage(0, 0);
  __syncthreads();
  int cur = 0;
  for (int k0 = 0; k0 < K; k0 += 64) {
    if (k0 + 64 < K) stage(cur ^ 1, k0 + 64);

#pragma unroll
    for (int kk = 0; kk < 2; ++kk) {
      bf16x8 af[NA], bfr[NB];
#pragma unroll
      for (int m = 0; m < NA; ++m) {
        int row = wr * WROWS + m * 16 + lr;
        af[m] = *(const bf16x8*)(&As[cur][row * 64 + (((kk * 4 + g) ^ (row & 7)) * 8)]);
      }
#pragma unroll
      for (int n = 0; n < NB; ++n) {
        int row = wc * (BN / 2) + n * 16 + lr;
        bfr[n] = *(const bf16x8*)(&Bs[cur][row * 64 + (((kk * 4 + g) ^ (row & 7)) * 8)]);
      }
      __builtin_amdgcn_s_setprio(1);
#pragma unroll
      for (int m = 0; m < NA; ++m)
#pragma unroll
        for (int n = 0; n < NB; ++n)
          acc[m][n] = mfma16(af[m], bfr[n], acc[m][n]);
      __builtin_amdgcn_s_setprio(0);
    }

    __syncthreads();
    cur ^= 1;
  }

#pragma unroll
  for (int m = 0; m < NA; ++m)
#pragma unroll
    for (int n = 0; n < NB; ++n)
#pragma unroll
      for (int r = 0; r < 4; ++r) {
        int row = row0 + wr * WROWS + m * 16 + g * 4 + r;
        int col = col0 + wc * (BN / 2) + n * 16 + lr;
        float v = acc[m][n][r];
        if constexpr (sizeof(OT) == 2) C[(size_t)row * N + col] = f2bf(v);
        else                            C[(size_t)row * N + col] = v;
      }
}

// ---------------- Flash attention + gate (Q norm/rope fused) — R22-proven ----------------
// 512 blocks x 4 waves (256 thr); block = 64 q-rows x 1 head; co-resident
// pairing qb=(j<16)?j:47-j -> paired blocks sum to 33 tile-units. KVBLK=64,
// 2 buffers, stage-before-compute, ONE __syncthreads/tile, no-max exp2 softmax.
__global__ __launch_bounds__(256) void attn_kernel(
    const unsigned short* __restrict__ qkv, const unsigned short* __restrict__ vTg,
    const int* __restrict__ seg,
    const float* __restrict__ cosb, const float* __restrict__ sinb,
    const float* __restrict__ qnw,
    unsigned short* __restrict__ attnb) {
  const int bid = blockIdx.x;
  const int h = bid & 15;
  const int j = bid >> 4;                 // 0..31
  const int qb = (j < 16) ? j : 47 - j;   // co-resident pairing: qb + (31-qb)
  const int kvh = h >> 2;
  const int tid = threadIdx.x;
  const int wave = tid >> 6, lane = tid & 63;
  const int g = lane >> 4, lr = lane & 15;
  const int qrow0 = qb * 64 + wave * 16;

  __shared__ unsigned short Ks[2][64 * 128];   // 32 KB
  __shared__ unsigned short Vt[2][128 * 64];   // 32 KB
  __shared__ unsigned short Plds[4][16][64];   // 8 KB (XOR col swizzle, no pad)

  const unsigned short* Kbase = qkv + KOFF + kvh * HD;         // row stride STRQKV
  const unsigned short* Vbase = vTg + (size_t)kvh * HD * T_SEQ;

  // 256 threads: K tile = 64 rows x 16 chunks = 1024 chunks (4 issues);
  //              V tile = 128 rows x 8 chunks = 1024 chunks (4 issues).
  auto stage = [&](int buf, int kv0) {
#pragma unroll
    for (int i = 0; i < 4; ++i) {
      int ci = i * 256 + tid;
      int row = ci >> 4, c16 = (ci & 15) ^ (row & 7);
      gload16(Kbase + (size_t)(kv0 + row) * STRQKV + c16 * 8, &Ks[buf][ci * 8]);
    }
#pragma unroll
    for (int i = 0; i < 4; ++i) {
      int ci = i * 256 + tid;
      int row = ci >> 3, ch = (ci & 7) ^ (row & 7);
      gload16(Vbase + (size_t)row * T_SEQ + kv0 + ch * 8, &Vt[buf][ci * 8]);
    }
  };

  const int ntiles = qb + 1;                   // 64-wide tiles
  const int segB = seg[qb * 64];
  int t_begin = 0;
  while (t_begin < ntiles - 1 && seg[t_begin * 64 + 63] < segB) ++t_begin;

  stage(0, t_begin * 64);

  // ---- fused Q RMSNorm + RoPE + scale (overlaps staging latency) ----
  const int t0 = qrow0 + lr;
  float xn[4][8];
  {
    float ssl = 0.f;
#pragma unroll
    for (int c = 0; c < 4; ++c) {
      bf16x8 tq = *(const bf16x8*)(qkv + (size_t)t0 * STRQKV + h * 256 + c * 32 + g * 8);
#pragma unroll
      for (int i = 0; i < 8; ++i) {
        float x = bf2f((unsigned short)tq[i]);
        xn[c][i] = x;
        ssl += x * x;
      }
    }
    ssl += __shfl_xor(ssl, 16, 64);
    ssl += __shfl_xor(ssl, 32, 64);
    float rstd = rsqrtf(ssl * (1.0f / 128.0f) + 1e-6f);
#pragma unroll
    for (int c = 0; c < 4; ++c)
#pragma unroll
      for (int i = 0; i < 8; ++i)
        xn[c][i] *= rstd * qnw[c * 32 + g * 8 + i];
  }
  bf16x8 qf[4];
#pragma unroll
  for (int c = 0; c < 4; ++c)
#pragma unroll
    for (int i = 0; i < 8; ++i) {
      int d = c * 32 + g * 8 + i;
      float rot = (c < 2) ? -xn[c + 2][i] : xn[c - 2][i];
      float ov = xn[c][i] * cosb[(size_t)t0 * HD + d] + rot * sinb[(size_t)t0 * HD + d];
      qf[c][i] = (short)f2bf(ov * (ATT_SCALE * LOG2E));   // log2-domain logits
    }

  bf16x8 vones;
#pragma unroll
  for (int i = 0; i < 8; ++i) vones[i] = (short)0x3F80;  // bf16 1.0

  int myrow[4], myseg[4];
#pragma unroll
  for (int r = 0; r < 4; ++r) {
    myrow[r] = qrow0 + g * 4 + r;
    myseg[r] = seg[myrow[r]];
  }
  const int seg_lo = seg[qrow0];
  const int seg_hi = seg[qrow0 + 15];

  f32x4 lacc = {};
  f32x4 oacc[8] = {};

  __syncthreads();  // first tile staged (drain)
  int cur = 0;
  for (int t = t_begin; t < ntiles; ++t) {
    const int kv0 = t * 64;
    if (t + 1 < ntiles) stage(cur ^ 1, kv0 + 64);  // overlaps compute below

    if (kv0 < qrow0 + 16 && seg[kv0 + 63] >= seg_lo) {  // wave-level causal/seg skip
      const unsigned short* ks = Ks[cur];
      const unsigned short* vt = Vt[cur];

      // ---- S = Q K^T : 16 x 64 (log2-domain) ----
      f32x4 sacc[4] = {};
      __builtin_amdgcn_s_setprio(1);
#pragma unroll
      for (int cc = 0; cc < 4; ++cc)
#pragma unroll
        for (int c = 0; c < 4; ++c) {
          int row = cc * 16 + lr;
          bf16x8 kf = *(const bf16x8*)(&ks[row * 128 + (((c * 4 + g) ^ (row & 7)) * 8)]);
          sacc[cc] = mfma16(qf[c], kf, sacc[cc]);
        }
      __builtin_amdgcn_s_setprio(0);

      // ---- P = exp2(S); Plds col' = col ^ ((row&3)<<4) ----
      const bool full = (kv0 + 64 <= qrow0) && (seg[kv0] == seg_hi);
      if (full) {
#pragma unroll
        for (int cc = 0; cc < 4; ++cc)
#pragma unroll
          for (int r = 0; r < 4; ++r)
            Plds[wave][g * 4 + r][((cc ^ r) * 16) + lr] = f2bf(exp2f(sacc[cc][r]));
      } else {
#pragma unroll
        for (int cc = 0; cc < 4; ++cc) {
          int kvi = kv0 + cc * 16 + lr;
          int ksg = seg[kvi];
#pragma unroll
          for (int r = 0; r < 4; ++r) {
            bool ok = (kvi <= myrow[r]) && (ksg == myseg[r]);
            float p = exp2f(sacc[cc][r]);
            Plds[wave][g * 4 + r][((cc ^ r) * 16) + lr] = f2bf(ok ? p : 0.0f);
          }
        }
      }

      // ---- PV: O += P[16x64] * V^T ; row-sum via ones-vector MFMA ----
      bf16x8 pf0 = *(const bf16x8*)(&Plds[wave][lr][(g * 8) ^ ((lr & 3) << 4)]);
      bf16x8 pf1 = *(const bf16x8*)(&Plds[wave][lr][(32 + g * 8) ^ ((lr & 3) << 4)]);
      __builtin_amdgcn_s_setprio(1);
#pragma unroll
      for (int n = 0; n < 8; ++n) {
        int row = n * 16 + lr;
        bf16x8 vf0 = *(const bf16x8*)(&vt[row * 64 + ((g ^ (row & 7)) * 8)]);
        oacc[n] = mfma16(pf0, vf0, oacc[n]);
        bf16x8 vf1 = *(const bf16x8*)(&vt[row * 64 + (((4 + g) ^ (row & 7)) * 8)]);
        oacc[n] = mfma16(pf1, vf1, oacc[n]);
      }
      lacc = mfma16(pf0, vones, lacc);
      lacc = mfma16(pf1, vones, lacc);
      __builtin_amdgcn_s_setprio(0);
    }

    __syncthreads();  // prefetch drained + all waves done with buf cur
    cur ^= 1;
  }

  // epilogue: normalize, sigmoid-gate, store bf16
#pragma unroll
  for (int n = 0; n < 8; ++n)
#pragma unroll
    for (int r = 0; r < 4; ++r) {
      int row = myrow[r];
      int d = n * 16 + lr;
      float o = oacc[n][r] / lacc[r];
      float gv = bf2f(qkv[(size_t)row * STRQKV + h * 256 + 128 + d]);
      float gate = 1.0f / (1.0f + __expf(-gv));
      attnb[(size_t)row * (NH * HD) + h * HD + d] = f2bf(o * gate);
    }
}

extern "C" void kernel_launch(void* const* d_in, const int* in_sizes, int n_in,
                              void* d_out, int out_size, void* d_ws, size_t ws_size,
                              hipStream_t stream) {
  const float* hidden = (const float*)d_in[0];
  const float* cosb   = (const float*)d_in[1];
  const float* sinb   = (const float*)d_in[2];
  const int*   seg    = (const int*)d_in[3];
  // d_in[4] = position_ids (arange; causal handled by index arithmetic)
  const float* wq     = (const float*)d_in[5];
  const float* wk     = (const float*)d_in[6];
  const float* wv     = (const float*)d_in[7];
  const float* wo     = (const float*)d_in[8];
  const float* qnw    = (const float*)d_in[9];
  const float* knw    = (const float*)d_in[10];
  float* out = (float*)d_out;

  // Workspace layout (liveness-aliased):
  //   [0,8)    Xb (hidden bf16)   -> dead after QKV GEMM -> Attnb
  //   [8,28)   Wqkvt [5120][2048] -> dead after QKV GEMM -> VT [16,18)
  //   [28,48)  Cqkv [2048][5120]  (q|gate|k|v; k normed/roped in place)
  //   [48,56)  Wot (only if ws_size >= 56MB; else Wot aliases [8,16) post-GEMM)
  char* ws = (char*)d_ws;
  const size_t MB = (size_t)1 << 20;
  const bool big = ws_size >= 56 * MB;
  unsigned short* Xb    = (unsigned short*)(ws + 0 * MB);
  unsigned short* Attnb = (unsigned short*)(ws + 0 * MB);
  unsigned short* Wqkvt = (unsigned short*)(ws + 8 * MB);
  unsigned short* VT    = (unsigned short*)(ws + 16 * MB);
  unsigned short* Cqkv  = (unsigned short*)(ws + 28 * MB);
  unsigned short* Wot   = (unsigned short*)(big ? (ws + 48 * MB) : (ws + 8 * MB));

  prep<<<big ? 7680 : 6656, 256, 0, stream>>>(hidden, wq, wk, wv, wo, Xb, Wqkvt, Wot);

  gemm_bt64<128, 160, unsigned short><<<dim3(STRQKV / 160, T_SEQ / 128), 512, 0, stream>>>(Xb, Wqkvt, Cqkv, T_SEQ, STRQKV, DMODEL);

  if (!big)
    transpose_wo<<<dim3(DMODEL / 32, DMODEL / 32), 256, 0, stream>>>(wo, Wot);

  normtv<<<5120, 256, 0, stream>>>(Cqkv, VT, cosb, sinb, knw);

  attn_kernel<<<512, 256, 0, stream>>>(Cqkv, VT, seg, cosb, sinb, qnw, Attnb);

  gemm_bt64<64, 128, float><<<dim3(DMODEL / 128, T_SEQ / 64), 512, 0, stream>>>(Attnb, Wot, out, T_SEQ, DMODEL, DMODEL);
}